// Round 6
// baseline (44.416 us; speedup 1.0000x reference)
//
#include <hip/hip_runtime.h>

// Haar 2x2 stride-2 analysis filter bank.
// N = 4**(PX_NUM-1) = 16 input channels (the reference comment "64" is wrong).
// x:   (8, 16, 512, 512) float32, NCHW contiguous  (33,554,432 elems, 128 MiB)
// out: (8, 64, 256, 256) float32                   (33,554,432 elems, 128 MiB)
// out channel i*16+j = filter i applied to input channel j, stride 2, VALID.
// Filter i (value[h][w] = col_i[h] * row_i[w]; correlation, no flip):
//   i=0: col h0,row h0 ; i=1: col h1,row h0 ; i=2: col h0,row h1 ; i=3: col h1,row h1
// h0 = [w1[0], w1[1]], h1 = [w2[0], w2[1]].

__global__ __launch_bounds__(256)
void haar_fwd_f32(const float* __restrict__ x,
                  const float* __restrict__ w1,
                  const float* __restrict__ w2,
                  float* __restrict__ out) {
    const float w00 = w1[0], w01 = w1[1];   // h0 taps
    const float w10 = w2[0], w11 = w2[1];   // h1 taps

    // One thread = one (b, j, oh) and 4 consecutive output columns.
    const unsigned TOTAL = 8u * 16u * 256u * 64u;   // 2,097,152
    const unsigned t = blockIdx.x * blockDim.x + threadIdx.x;
    if (t >= TOTAL) return;

    const unsigned q  = t & 63u;     // quad index within output row (ow = 4q..4q+3)
    const unsigned r  = t >> 6;
    const unsigned oh = r & 255u;    // output row
    const unsigned bj = r >> 8;      // b*16 + j, 0..127
    const unsigned b  = bj >> 4, j = bj & 15u;

    // Input: rows 2*oh, 2*oh+1, cols 8q .. 8q+7 of plane bj
    const size_t in_base = ((size_t)bj * 512u + 2u * oh) * 512u + 8u * q;
    const float4 r0a = *reinterpret_cast<const float4*>(x + in_base);
    const float4 r0b = *reinterpret_cast<const float4*>(x + in_base + 4);
    const float4 r1a = *reinterpret_cast<const float4*>(x + in_base + 512);
    const float4 r1b = *reinterpret_cast<const float4*>(x + in_base + 516);

    float4 o0, o1, o2, o3;

    // (A,B,C,D) = (top-left, top-right, bottom-left, bottom-right) of 2x2 patch
    #define HAAR_PX(A, B, C, D, F)                                     \
    {                                                                  \
        const float ra0 = w00 * (A) + w01 * (B);  /* h0 row, top    */ \
        const float ra1 = w00 * (C) + w01 * (D);  /* h0 row, bottom */ \
        const float rb0 = w10 * (A) + w11 * (B);  /* h1 row, top    */ \
        const float rb1 = w10 * (C) + w11 * (D);  /* h1 row, bottom */ \
        o0.F = w00 * ra0 + w01 * ra1;                                  \
        o1.F = w10 * ra0 + w11 * ra1;                                  \
        o2.F = w00 * rb0 + w01 * rb1;                                  \
        o3.F = w10 * rb0 + w11 * rb1;                                  \
    }

    HAAR_PX(r0a.x, r0a.y, r1a.x, r1a.y, x)
    HAAR_PX(r0a.z, r0a.w, r1a.z, r1a.w, y)
    HAAR_PX(r0b.x, r0b.y, r1b.x, r1b.y, z)
    HAAR_PX(r0b.z, r0b.w, r1b.z, r1b.w, w)

    #undef HAAR_PX

    // Output: channel (i*16 + j) of batch b, row oh, cols 4q..4q+3.
    // Filter blocks are 16 channels = 16*256*256 elems apart.
    const size_t CH = (size_t)16 * 256 * 256;   // 1,048,576
    const size_t out_base = (((size_t)b * 64u + j) * 256u + oh) * 256u + 4u * q;

    *reinterpret_cast<float4*>(out + out_base)          = o0;
    *reinterpret_cast<float4*>(out + out_base + 1 * CH) = o1;
    *reinterpret_cast<float4*>(out + out_base + 2 * CH) = o2;
    *reinterpret_cast<float4*>(out + out_base + 3 * CH) = o3;
}

extern "C" void kernel_launch(void* const* d_in, const int* in_sizes, int n_in,
                              void* d_out, int out_size, void* d_ws, size_t ws_size,
                              hipStream_t stream) {
    // x = largest input; w1/w2 = the remaining two in index order (robust to
    // any argument-order convention; free).
    int xi = 0;
    for (int i = 1; i < n_in; ++i)
        if (in_sizes[i] > in_sizes[xi]) xi = i;
    int wa = -1, wb = -1;
    for (int i = 0; i < n_in; ++i) {
        if (i == xi) continue;
        if (wa < 0) wa = i; else if (wb < 0) wb = i;
    }

    const float* x  = (const float*)d_in[xi];
    const float* w1 = (const float*)d_in[wa];
    const float* w2 = (const float*)d_in[wb];
    float* out = (float*)d_out;

    const unsigned TOTAL = 8u * 16u * 256u * 64u;   // 2,097,152 threads
    const int block = 256;
    const int grid  = (int)(TOTAL / block);         // 8,192 blocks
    haar_fwd_f32<<<grid, block, 0, stream>>>(x, w1, w2, out);
}